// Round 6
// baseline (1132.780 us; speedup 1.0000x reference)
//
#include <hip/hip_runtime.h>
#include <hip/hip_bf16.h>
#include <hip/hip_cooperative_groups.h>

namespace cg = cooperative_groups;

// Problem dims
#define B_ 1024
#define I_ 512
#define O_ 512
#define M_ 8
#define R_ 512
#define A_ 16
#define D_ 128   // M_*A_
#define NLEV 11  // squaring levels: k = 2^j, j=0..11

using bf16 = __hip_bfloat16;
typedef __attribute__((ext_vector_type(8))) short bf16x8;
typedef __attribute__((ext_vector_type(4))) float f32x4;

__device__ __forceinline__ short f2b(float x){
  __hip_bfloat16 h = __float2bfloat16(x);
  union { __hip_bfloat16 h; short s; } u; u.h = h; return u.s;
}
__device__ __forceinline__ float s2f(short s){
  union { short s[2]; float f; } u; u.s[0] = 0; u.s[1] = s; return u.f;
}

// ---------------------------------------------------------------------------
// MFMA bf16 GEMM template (main pipeline): 64x64 tile, BK=32, 256 threads.
// Operands via fp32 functors, converted to bf16 in LDS. (unchanged from R5)
// ---------------------------------------------------------------------------
template<int SKL, class FA, class FB, class FC>
__global__ __launch_bounds__(256) void gemm_mfma(FA fa, FB fb, FC fc, int Ktot){
  __shared__ __align__(16) short As[64][40];   // [m][k]
  __shared__ __align__(16) short Bs[64][40];   // [n][k]
  const int t = threadIdx.x;
  const int wv = t >> 6, lane = t & 63;
  const int row0 = blockIdx.y * 64, col0 = blockIdx.x * 64;
  const int kseg = Ktot >> SKL;
  const int kbeg = (blockIdx.z & ((1 << SKL) - 1)) * kseg;
  const int sr = t >> 2, sk = (t & 3) * 8;
  const int wr = (wv >> 1) * 32, wc = (wv & 1) * 32;
  const int fm = lane & 15, fq = lane >> 4;
  f32x4 zz = {0.f, 0.f, 0.f, 0.f};
  f32x4 acc[2][2] = {{zz, zz}, {zz, zz}};
  for (int k0 = 0; k0 < kseg; k0 += 32){
    float av[8], bv[8];
    #pragma unroll
    for (int j = 0; j < 8; ++j) av[j] = fa(row0 + sr, kbeg + k0 + sk + j);
    #pragma unroll
    for (int j = 0; j < 8; ++j) bv[j] = fb(kbeg + k0 + sk + j, col0 + sr);
    __syncthreads();
    bf16x8 pa, pb;
    #pragma unroll
    for (int j = 0; j < 8; ++j){ pa[j] = f2b(av[j]); pb[j] = f2b(bv[j]); }
    *(bf16x8*)&As[sr][sk] = pa;
    *(bf16x8*)&Bs[sr][sk] = pb;
    __syncthreads();
    bf16x8 af[2], bfr[2];
    #pragma unroll
    for (int i = 0; i < 2; ++i){
      af[i]  = *(const bf16x8*)&As[wr + i * 16 + fm][fq * 8];
      bfr[i] = *(const bf16x8*)&Bs[wc + i * 16 + fm][fq * 8];
    }
    #pragma unroll
    for (int i = 0; i < 2; ++i)
      #pragma unroll
      for (int j = 0; j < 2; ++j)
        acc[i][j] = __builtin_amdgcn_mfma_f32_16x16x32_bf16(af[i], bfr[j], acc[i][j], 0, 0, 0);
  }
  #pragma unroll
  for (int i = 0; i < 2; ++i)
    #pragma unroll
    for (int j = 0; j < 2; ++j)
      #pragma unroll
      for (int r = 0; r < 4; ++r)
        fc(row0 + wr + i * 16 + fq * 4 + r, col0 + wc + j * 16 + fm, acc[i][j][r]);
}

// ------------------------- operand functors (fp32 sources) ------------------
struct AXi  { const float* p; __device__ float operator()(int r, int k) const { return p[r * I_ + k]; } };
struct BWx  { const float* p; __device__ float operator()(int k, int c) const { return p[(c >> 4) * (512 * A_) + k * A_ + (c & 15)]; } };
struct CQ   { float* p; __device__ void operator()(int r, int c, float v) const { p[r * D_ + c] = v; } };
struct ASi  { const float* p; __device__ float operator()(int r, int k) const { return p[r * R_ + k]; } };
struct CKV  { float* p; __device__ void operator()(int r, int c, float v) const {
  int b = r >> 3, n = r & 7, m = c >> 4, a = c & 15;
  p[b * 1024 + m * 128 + n * 16 + a] = v; } };
struct APre { const float* ui; const float* si; const float* sc; __device__ float operator()(int r, int k) const {
  int m = blockIdx.z;
  if (k < D_) return ui[(r * M_ + m) * D_ + k];
  return sc[m] * si[(r * M_ + m) * R_ + (k - D_)]; } };
struct BPre { const float* win; const float* w; __device__ float operator()(int k, int c) const {
  int m = blockIdx.z;
  if (k < D_) return win[m * (D_ * R_) + k * R_ + c];
  return w[m * (R_ * R_) + (k - D_) * R_ + c]; } };
struct CPre { float* p; __device__ void operator()(int r, int c, float v) const {
  p[(r * M_ + blockIdx.z) * R_ + c] = v; } };
struct AYi  { const float* p; __device__ float operator()(int r, int k) const { return p[r * 4096 + k]; } };
struct BYi  { const float* p; __device__ float operator()(int k, int c) const { return p[k * O_ + c]; } };
struct CYiA { float* p; __device__ void operator()(int r, int c, float v) const { atomicAdd(&p[r * O_ + c], v); } };

// ---------------------------------------------------------------------------
// Cooperative eigen chain: ONE kernel does prep + NLEV squaring levels + rho.
// 512 blocks x 256 threads; each block owns one 64x64 tile (8 units x 64
// tiles). X/XT bf16 ping-pong between sets; per-level normalization scale
// applied in the epilogue (pending-scale algebra identical to R5).
// ---------------------------------------------------------------------------
__global__ __launch_bounds__(256) void k_chain(const float* W,
                                               short* Xa, short* XTa,
                                               short* Xb, short* XTb,
                                               float* norm2, const float* srv, float* sscal){
  cg::grid_group grid = cg::this_grid();
  __shared__ __align__(16) short smem[5120];                 // 10.2 KB
  short (*As)[40] = (short(*)[40])smem;
  short (*Bs)[40] = (short(*)[40])(smem + 2560);
  short (*Tr)[66] = (short(*)[66])smem;                      // overlay (8.4 KB)

  const int t = threadIdx.x, blk = blockIdx.x;
  const int u = blk >> 6, tile = blk & 63;
  const int row0 = (tile >> 3) * 64, col0 = (tile & 7) * 64;
  const size_t off = (size_t)u * (R_ * R_);
  const int lane = t & 63;

  // phase -1: zero norm2
  if (blk == 0 && t < 8 * (NLEV + 1)) norm2[t] = 0.f;
  grid.sync();

  // phase 0: prep — X0 = bf16(W), X0^T, norm2[0] over rounded values
  {
    float ss = 0.f;
    short vals[16];
    #pragma unroll
    for (int l = 0; l < 16; ++l){
      int idx = l * 256 + t, r = idx >> 6, c = idx & 63;
      short b = f2b(W[off + (row0 + r) * R_ + col0 + c]);
      vals[l] = b;
      float vb = s2f(b);
      ss = fmaf(vb, vb, ss);
      Xa[off + (row0 + r) * R_ + col0 + c] = b;
    }
    #pragma unroll
    for (int l = 0; l < 16; ++l){ int idx = l * 256 + t; Tr[idx >> 6][idx & 63] = vals[l]; }
    __syncthreads();
    #pragma unroll
    for (int l = 0; l < 16; ++l){
      int idx = l * 256 + t, r = idx >> 6, c = idx & 63;
      XTa[off + (col0 + r) * R_ + row0 + c] = Tr[c][r];
    }
    #pragma unroll
    for (int o = 32; o > 0; o >>= 1) ss += __shfl_xor(ss, o, 64);
    if (lane == 0) atomicAdd(&norm2[u], ss);
  }
  grid.sync();

  // levels 1..NLEV
  const int wv = t >> 6;
  const int sr_ = t >> 2, sk = (t & 3) * 8;
  const int wr = (wv >> 1) * 32, wc = (wv & 1) * 32;
  const int fm = lane & 15, fq = lane >> 4;
  for (int lev = 1; lev <= NLEV; ++lev){
    const short* Xr  = (lev & 1) ? Xa  : Xb;
    const short* XTr = (lev & 1) ? XTa : XTb;
    short* Xw  = (lev & 1) ? Xb  : Xa;
    short* XTw = (lev & 1) ? XTb : XTa;
    const float s2 = 1.f / __hip_atomic_load(&norm2[(lev - 1) * 8 + u],
                                             __ATOMIC_RELAXED, __HIP_MEMORY_SCOPE_AGENT);
    f32x4 zz = {0.f, 0.f, 0.f, 0.f};
    f32x4 acc[2][2] = {{zz, zz}, {zz, zz}};
    for (int k0 = 0; k0 < R_; k0 += 32){
      bf16x8 a8 = *(const bf16x8*)&Xr [off + (row0 + sr_) * R_ + k0 + sk];
      bf16x8 b8 = *(const bf16x8*)&XTr[off + (col0 + sr_) * R_ + k0 + sk];
      __syncthreads();
      *(bf16x8*)&As[sr_][sk] = a8;
      *(bf16x8*)&Bs[sr_][sk] = b8;
      __syncthreads();
      bf16x8 af[2], bfr[2];
      #pragma unroll
      for (int i = 0; i < 2; ++i){
        af[i]  = *(const bf16x8*)&As[wr + i * 16 + fm][fq * 8];
        bfr[i] = *(const bf16x8*)&Bs[wc + i * 16 + fm][fq * 8];
      }
      #pragma unroll
      for (int i = 0; i < 2; ++i)
        #pragma unroll
        for (int j = 0; j < 2; ++j)
          acc[i][j] = __builtin_amdgcn_mfma_f32_16x16x32_bf16(af[i], bfr[j], acc[i][j], 0, 0, 0);
    }
    // epilogue: scale, round, write X, LDS-transpose -> XT, accumulate norm
    __syncthreads();                      // K-loop ds_reads done before Tr overlay
    float ss = 0.f;
    #pragma unroll
    for (int i = 0; i < 2; ++i)
      #pragma unroll
      for (int j = 0; j < 2; ++j)
        #pragma unroll
        for (int r = 0; r < 4; ++r){
          int lr = wr + i * 16 + fq * 4 + r, lc = wc + j * 16 + fm;
          short b = f2b(acc[i][j][r] * s2);
          float vb = s2f(b);
          ss = fmaf(vb, vb, ss);
          Xw[off + (row0 + lr) * R_ + col0 + lc] = b;
          Tr[lr][lc] = b;
        }
    __syncthreads();
    #pragma unroll
    for (int l = 0; l < 16; ++l){
      int idx = l * 256 + t, r = idx >> 6, c = idx & 63;
      XTw[off + (col0 + r) * R_ + row0 + c] = Tr[c][r];
    }
    #pragma unroll
    for (int o = 32; o > 0; o >>= 1) ss += __shfl_xor(ss, o, 64);
    if (lane == 0) atomicAdd(&norm2[lev * 8 + u], ss);
    grid.sync();
  }

  // rho: L_j = 2 L_{j-1} + 0.5 ln n2_j ; lnrho = (L11 - 2 L10 + L9)/512
  if (blk == 0 && t < 8){
    float L = 0.5f * logf(__hip_atomic_load(&norm2[t], __ATOMIC_RELAXED, __HIP_MEMORY_SCOPE_AGENT));
    float L9 = 0.f, L10 = 0.f, L11 = 0.f;
    for (int j = 1; j <= NLEV; ++j){
      float n2 = __hip_atomic_load(&norm2[j * 8 + t], __ATOMIC_RELAXED, __HIP_MEMORY_SCOPE_AGENT);
      L = 2.f * L + 0.5f * logf(n2);
      if (j == 9)  L9  = L;
      if (j == 10) L10 = L;
      if (j == 11) L11 = L;
    }
    float lnr = (L11 - 2.f * L10 + L9) * (1.f / 512.f);
    sscal[t] = srv[t] / expf(lnr);
  }
}

__global__ __launch_bounds__(256) void k_zero(float* p){
  const int t = threadIdx.x;
  #pragma unroll
  for (int e = 0; e < 4; ++e) p[blockIdx.x * 1024 + e * 256 + t] = 0.f;
}

// ---------------------------------------------------------------------------
// Attention: one wave per (b,m). lane = q*8+n.
// ---------------------------------------------------------------------------
__global__ __launch_bounds__(256) void k_attn(const float* Q, const float* K, const float* V, float* Ui){
  __shared__ float sQ[4][128], sK[4][128], sV[4][128], sA[4][64];
  const int wib = threadIdx.x >> 6, lane = threadIdx.x & 63;
  const int w = blockIdx.x * 4 + wib;
  const int b = w >> 3, m = w & 7;
  for (int e = lane; e < 128; e += 64){
    sQ[wib][e] = Q[b * 128 + e];
    sK[wib][e] = K[b * 1024 + m * 128 + e];
    sV[wib][e] = V[b * 1024 + m * 128 + e];
  }
  __syncthreads();
  const int q = lane >> 3, n = lane & 7;
  float s = 0.f;
  #pragma unroll
  for (int a = 0; a < 16; ++a) s = fmaf(sQ[wib][q * 16 + a], sK[wib][n * 16 + a], s);
  float mx = s;
  for (int d2 = 1; d2 < 8; d2 <<= 1) mx = fmaxf(mx, __shfl_xor(mx, d2, 64));
  float p = expf(s - mx);
  float sm = p;
  for (int d2 = 1; d2 < 8; d2 <<= 1) sm += __shfl_xor(sm, d2, 64);
  float ai = p / (sm * 11.313708498984761f);   // softmax then /sqrt(128)
  sA[wib][q * 8 + n] = ai;
  __syncthreads();
  for (int e = lane; e < 128; e += 64){
    int q2 = e >> 4, a2 = e & 15;
    float acc = 0.f;
    #pragma unroll
    for (int n2 = 0; n2 < 8; ++n2) acc = fmaf(sA[wib][q2 * 8 + n2], sV[wib][n2 * 16 + a2], acc);
    Ui[(b * 8 + m) * 128 + e] = acc;
  }
}

// Snew = (1-lr)*Si + lr*tanh(pre + bias)
__global__ __launch_bounds__(256) void k_final_ew(const float* pre, const float* bias, const float* lr,
                                                  const float* Si, float* outSnew){
  const int t = threadIdx.x;
  for (int e = 0; e < 4; ++e){
    int idx = blockIdx.x * 1024 + e * 256 + t;
    int m = (idx >> 9) & 7, r = idx & 511;
    float v  = pre[idx] + bias[m * 512 + r];
    float tt = tanhf(v);
    float l  = lr[m];
    outSnew[idx] = (1.f - l) * Si[idx] + l * tt;
  }
}

// ---------------------------------------------------------------------------
extern "C" void kernel_launch(void* const* d_in, const int* in_sizes, int n_in,
                              void* d_out, int out_size, void* d_ws, size_t ws_size,
                              hipStream_t stream) {
  const float* Xi   = (const float*)d_in[0];
  const float* Si   = (const float*)d_in[1];
  const float* Wq   = (const float*)d_in[2];
  const float* Wk   = (const float*)d_in[3];
  const float* Wv   = (const float*)d_in[4];
  const float* Wout = (const float*)d_in[5];
  const float* W    = (const float*)d_in[6];
  const float* Win  = (const float*)d_in[7];
  const float* bias = (const float*)d_in[8];
  const float* sr   = (const float*)d_in[9];
  const float* lr   = (const float*)d_in[10];

  float* ws = (float*)d_ws;
  // chain buffers (bf16 sets, ping-pong) occupy ws[0 .. 4,194,304) floats;
  // preb aliases the same region (used only after the chain is done).
  short* Xa    = (short*)(ws + 0);         // 2M shorts (4 MB)
  short* XTa   = (short*)(ws + 1048576);
  short* Xb    = (short*)(ws + 2097152);
  short* XTb   = (short*)(ws + 3145728);
  float* preb  = ws + 0;                   // 4,194,304 floats [B,M,R]
  float* Qb    = ws + 4194304;   // 131,072
  float* Kb    = ws + 4325376;   // 1,048,576
  float* Vb    = ws + 5373952;   // 1,048,576
  float* Uib   = ws + 6422528;   // 1,048,576
  float* norm2 = ws + 7471104;   // 96
  float* sscal = ws + 7471200;   // 8

  float* outYi   = (float*)d_out;            // [1024,512]
  float* outSnew = (float*)d_out + 524288;   // [1024,8,512]

  // ---- spectral radius chain: one cooperative kernel ----
  k_zero<<<512, 256, 0, stream>>>(outYi);    // for split-K atomic Yi epilogue
  {
    void* args[] = {(void*)&W, (void*)&Xa, (void*)&XTa, (void*)&Xb, (void*)&XTb,
                    (void*)&norm2, (void*)&sr, (void*)&sscal};
    hipLaunchCooperativeKernel((const void*)k_chain, dim3(512), dim3(256), args, 0, stream);
  }

  // ---- main pipeline (MFMA bf16) ----
  gemm_mfma<0><<<dim3(2, 16), 256, 0, stream>>>(AXi{Xi}, BWx{Wq}, CQ{Qb}, 512);
  gemm_mfma<0><<<dim3(2, 128), 256, 0, stream>>>(ASi{Si}, BWx{Wk}, CKV{Kb}, 512);
  gemm_mfma<0><<<dim3(2, 128), 256, 0, stream>>>(ASi{Si}, BWx{Wv}, CKV{Vb}, 512);
  k_attn<<<2048, 256, 0, stream>>>(Qb, Kb, Vb, Uib);
  gemm_mfma<0><<<dim3(8, 16, 8), 256, 0, stream>>>(APre{Uib, Si, sscal}, BPre{Win, W}, CPre{preb}, 640);
  k_final_ew<<<4096, 256, 0, stream>>>(preb, bias, lr, Si, outSnew);
  gemm_mfma<2><<<dim3(8, 16, 4), 256, 0, stream>>>(AYi{outSnew}, BYi{Wout}, CYiA{outYi}, 4096);
}

// Round 7
// 702.485 us; speedup vs baseline: 1.6125x; 1.6125x over previous
//
#include <hip/hip_runtime.h>
#include <hip/hip_bf16.h>

// Problem dims
#define B_ 1024
#define I_ 512
#define O_ 512
#define M_ 8
#define R_ 512
#define A_ 16
#define D_ 128   // M_*A_
#define NLEV 11  // squaring levels: k = 2^j, j=0..11

using bf16 = __hip_bfloat16;
typedef __attribute__((ext_vector_type(8))) short bf16x8;
typedef __attribute__((ext_vector_type(4))) float f32x4;

__device__ __forceinline__ short f2b(float x){
  __hip_bfloat16 h = __float2bfloat16(x);
  union { __hip_bfloat16 h; short s; } u; u.h = h; return u.s;
}
__device__ __forceinline__ float s2f(short s){
  union { short s[2]; float f; } u; u.s[0] = 0; u.s[1] = s; return u.f;
}

// ---------------------------------------------------------------------------
// MFMA bf16 GEMM template (main pipeline): 64x64 tile, BK=32, 256 threads.
// Operands via fp32 functors, converted to bf16 in LDS. (unchanged from R5)
// ---------------------------------------------------------------------------
template<int SKL, class FA, class FB, class FC>
__global__ __launch_bounds__(256) void gemm_mfma(FA fa, FB fb, FC fc, int Ktot){
  __shared__ __align__(16) short As[64][40];   // [m][k]
  __shared__ __align__(16) short Bs[64][40];   // [n][k]
  const int t = threadIdx.x;
  const int wv = t >> 6, lane = t & 63;
  const int row0 = blockIdx.y * 64, col0 = blockIdx.x * 64;
  const int kseg = Ktot >> SKL;
  const int kbeg = (blockIdx.z & ((1 << SKL) - 1)) * kseg;
  const int sr = t >> 2, sk = (t & 3) * 8;
  const int wr = (wv >> 1) * 32, wc = (wv & 1) * 32;
  const int fm = lane & 15, fq = lane >> 4;
  f32x4 zz = {0.f, 0.f, 0.f, 0.f};
  f32x4 acc[2][2] = {{zz, zz}, {zz, zz}};
  for (int k0 = 0; k0 < kseg; k0 += 32){
    float av[8], bv[8];
    #pragma unroll
    for (int j = 0; j < 8; ++j) av[j] = fa(row0 + sr, kbeg + k0 + sk + j);
    #pragma unroll
    for (int j = 0; j < 8; ++j) bv[j] = fb(kbeg + k0 + sk + j, col0 + sr);
    __syncthreads();
    bf16x8 pa, pb;
    #pragma unroll
    for (int j = 0; j < 8; ++j){ pa[j] = f2b(av[j]); pb[j] = f2b(bv[j]); }
    *(bf16x8*)&As[sr][sk] = pa;
    *(bf16x8*)&Bs[sr][sk] = pb;
    __syncthreads();
    bf16x8 af[2], bfr[2];
    #pragma unroll
    for (int i = 0; i < 2; ++i){
      af[i]  = *(const bf16x8*)&As[wr + i * 16 + fm][fq * 8];
      bfr[i] = *(const bf16x8*)&Bs[wc + i * 16 + fm][fq * 8];
    }
    #pragma unroll
    for (int i = 0; i < 2; ++i)
      #pragma unroll
      for (int j = 0; j < 2; ++j)
        acc[i][j] = __builtin_amdgcn_mfma_f32_16x16x32_bf16(af[i], bfr[j], acc[i][j], 0, 0, 0);
  }
  #pragma unroll
  for (int i = 0; i < 2; ++i)
    #pragma unroll
    for (int j = 0; j < 2; ++j)
      #pragma unroll
      for (int r = 0; r < 4; ++r)
        fc(row0 + wr + i * 16 + fq * 4 + r, col0 + wc + j * 16 + fm, acc[i][j][r]);
}

// ------------------------- operand functors (fp32 sources) ------------------
struct AXi  { const float* p; __device__ float operator()(int r, int k) const { return p[r * I_ + k]; } };
struct BWx  { const float* p; __device__ float operator()(int k, int c) const { return p[(c >> 4) * (512 * A_) + k * A_ + (c & 15)]; } };
struct CQ   { float* p; __device__ void operator()(int r, int c, float v) const { p[r * D_ + c] = v; } };
struct ASi  { const float* p; __device__ float operator()(int r, int k) const { return p[r * R_ + k]; } };
struct CKV  { float* p; __device__ void operator()(int r, int c, float v) const {
  int b = r >> 3, n = r & 7, m = c >> 4, a = c & 15;
  p[b * 1024 + m * 128 + n * 16 + a] = v; } };
struct APre { const float* ui; const float* si; const float* sc; __device__ float operator()(int r, int k) const {
  int m = blockIdx.z;
  if (k < D_) return ui[(r * M_ + m) * D_ + k];
  return sc[m] * si[(r * M_ + m) * R_ + (k - D_)]; } };
struct BPre { const float* win; const float* w; __device__ float operator()(int k, int c) const {
  int m = blockIdx.z;
  if (k < D_) return win[m * (D_ * R_) + k * R_ + c];
  return w[m * (R_ * R_) + (k - D_) * R_ + c]; } };
struct CPre { float* p; __device__ void operator()(int r, int c, float v) const {
  p[(r * M_ + blockIdx.z) * R_ + c] = v; } };
struct AYi  { const float* p; __device__ float operator()(int r, int k) const { return p[r * 4096 + k]; } };
struct BYi  { const float* p; __device__ float operator()(int k, int c) const { return p[k * O_ + c]; } };
struct CYiA { float* p; __device__ void operator()(int r, int c, float v) const { atomicAdd(&p[r * O_ + c], v); } };

// ---------------------------------------------------------------------------
// Eigen chain v3: per-level kernels, XCD-local (blockIdx.x = unit), barrier-
// free K-loop with direct global->VGPR fragment loads (X=[m][k], XT=[n][k]
// are exactly MFMA A/B frag layouts), register double-buffer. Scale applied
// in epilogue (pending-scale algebra; numerics identical to R5/R6).
// ---------------------------------------------------------------------------
__global__ void k_init(float* norm2){
  int t = threadIdx.x;
  if (t < 8 * (NLEV + 1)) norm2[t] = 0.f;
}

__global__ __launch_bounds__(256) void k_zero(float* p){
  const int t = threadIdx.x;
  #pragma unroll
  for (int e = 0; e < 4; ++e) p[blockIdx.x * 1024 + e * 256 + t] = 0.f;
}

// W (fp32) -> X0 bf16 + X0^T bf16 + norm2[0] (over bf16-rounded values)
__global__ __launch_bounds__(256) void k_prep2(const float* __restrict__ W, short* __restrict__ X,
                                               short* __restrict__ XT, float* __restrict__ norm2){
  __shared__ short Tr[64][66];
  const int u = blockIdx.x, tile = blockIdx.y;
  const int row0 = (tile >> 3) * 64, col0 = (tile & 7) * 64;
  const size_t off = (size_t)u * (R_ * R_);
  const int t = threadIdx.x, lane = t & 63;
  float ss = 0.f;
  #pragma unroll
  for (int l = 0; l < 16; ++l){
    int idx = l * 256 + t, r = idx >> 6, c = idx & 63;
    short b = f2b(W[off + (size_t)(row0 + r) * R_ + col0 + c]);
    float vb = s2f(b);
    ss = fmaf(vb, vb, ss);
    X[off + (size_t)(row0 + r) * R_ + col0 + c] = b;
    Tr[r][c] = b;
  }
  __syncthreads();
  #pragma unroll
  for (int l = 0; l < 16; ++l){
    int idx = l * 256 + t, r = idx >> 6, c = idx & 63;
    XT[off + (size_t)(col0 + r) * R_ + row0 + c] = Tr[c][r];
  }
  #pragma unroll
  for (int o = 32; o > 0; o >>= 1) ss += __shfl_xor(ss, o, 64);
  if (lane == 0) atomicAdd(&norm2[u], ss);
}

// One squaring level: X_lev = bf16(s2 * (X*X)), plus X_lev^T and norm2[lev].
__global__ __launch_bounds__(256) void k_sq3(const short* __restrict__ Xr, const short* __restrict__ XTr,
                                             short* __restrict__ Xw, short* __restrict__ XTw,
                                             float* __restrict__ norm2, int lev){
  __shared__ short Tr[64][66];
  const int u = blockIdx.x, tile = blockIdx.y;     // blockIdx.x = unit -> XCD-local
  const int row0 = (tile >> 3) * 64, col0 = (tile & 7) * 64;
  const size_t off = (size_t)u * (R_ * R_);
  const int t = threadIdx.x, wv = t >> 6, lane = t & 63;
  const int wr = (wv >> 1) * 32, wc = (wv & 1) * 32;
  const int fm = lane & 15, fq = lane >> 4, ko = fq * 8;
  const float s2 = 1.f / norm2[(lev - 1) * 8 + u];
  const short* A0 = Xr  + off + (size_t)(row0 + wr + fm) * R_ + ko;
  const short* A1 = A0 + 16 * R_;
  const short* B0 = XTr + off + (size_t)(col0 + wc + fm) * R_ + ko;
  const short* B1 = B0 + 16 * R_;
  f32x4 zz = {0.f, 0.f, 0.f, 0.f};
  f32x4 acc[2][2] = {{zz, zz}, {zz, zz}};
  bf16x8 a0 = *(const bf16x8*)A0, a1 = *(const bf16x8*)A1;
  bf16x8 b0 = *(const bf16x8*)B0, b1 = *(const bf16x8*)B1;
  #pragma unroll
  for (int kk = 1; kk <= 16; ++kk){
    bf16x8 na0, na1, nb0, nb1;
    if (kk < 16){
      na0 = *(const bf16x8*)(A0 + kk * 32);
      na1 = *(const bf16x8*)(A1 + kk * 32);
      nb0 = *(const bf16x8*)(B0 + kk * 32);
      nb1 = *(const bf16x8*)(B1 + kk * 32);
    }
    acc[0][0] = __builtin_amdgcn_mfma_f32_16x16x32_bf16(a0, b0, acc[0][0], 0, 0, 0);
    acc[0][1] = __builtin_amdgcn_mfma_f32_16x16x32_bf16(a0, b1, acc[0][1], 0, 0, 0);
    acc[1][0] = __builtin_amdgcn_mfma_f32_16x16x32_bf16(a1, b0, acc[1][0], 0, 0, 0);
    acc[1][1] = __builtin_amdgcn_mfma_f32_16x16x32_bf16(a1, b1, acc[1][1], 0, 0, 0);
    a0 = na0; a1 = na1; b0 = nb0; b1 = nb1;
  }
  // epilogue: scale, round, write X, LDS-transpose -> XT, accumulate norm
  float ss = 0.f;
  #pragma unroll
  for (int i = 0; i < 2; ++i)
    #pragma unroll
    for (int j = 0; j < 2; ++j)
      #pragma unroll
      for (int r = 0; r < 4; ++r){
        int lr = wr + i * 16 + fq * 4 + r, lc = wc + j * 16 + fm;
        short b = f2b(acc[i][j][r] * s2);
        float vb = s2f(b);
        ss = fmaf(vb, vb, ss);
        Xw[off + (size_t)(row0 + lr) * R_ + col0 + lc] = b;
        Tr[lr][lc] = b;
      }
  __syncthreads();
  #pragma unroll
  for (int l = 0; l < 16; ++l){
    int idx = l * 256 + t, r = idx >> 6, c = idx & 63;
    XTw[off + (size_t)(col0 + r) * R_ + row0 + c] = Tr[c][r];
  }
  #pragma unroll
  for (int o = 32; o > 0; o >>= 1) ss += __shfl_xor(ss, o, 64);
  if (lane == 0) atomicAdd(&norm2[lev * 8 + u], ss);
}

// L_j = 2 L_{j-1} + 0.5 ln n2_j ; lnrho = (L11 - 2 L10 + L9)/512
__global__ void k_rho(const float* norm2, const float* sr, float* sscale){
  int t = threadIdx.x;
  if (t < 8){
    float L = 0.5f * logf(norm2[t]);
    float L9 = 0.f, L10 = 0.f, L11 = 0.f;
    for (int j = 1; j <= NLEV; ++j){
      L = 2.f * L + 0.5f * logf(norm2[j * 8 + t]);
      if (j == 9)  L9  = L;
      if (j == 10) L10 = L;
      if (j == 11) L11 = L;
    }
    float lnr = (L11 - 2.f * L10 + L9) * (1.f / 512.f);
    sscale[t] = sr[t] / expf(lnr);
  }
}

// ---------------------------------------------------------------------------
// Attention: one wave per (b,m). lane = q*8+n.
// ---------------------------------------------------------------------------
__global__ __launch_bounds__(256) void k_attn(const float* Q, const float* K, const float* V, float* Ui){
  __shared__ float sQ[4][128], sK[4][128], sV[4][128], sA[4][64];
  const int wib = threadIdx.x >> 6, lane = threadIdx.x & 63;
  const int w = blockIdx.x * 4 + wib;
  const int b = w >> 3, m = w & 7;
  for (int e = lane; e < 128; e += 64){
    sQ[wib][e] = Q[b * 128 + e];
    sK[wib][e] = K[b * 1024 + m * 128 + e];
    sV[wib][e] = V[b * 1024 + m * 128 + e];
  }
  __syncthreads();
  const int q = lane >> 3, n = lane & 7;
  float s = 0.f;
  #pragma unroll
  for (int a = 0; a < 16; ++a) s = fmaf(sQ[wib][q * 16 + a], sK[wib][n * 16 + a], s);
  float mx = s;
  for (int d2 = 1; d2 < 8; d2 <<= 1) mx = fmaxf(mx, __shfl_xor(mx, d2, 64));
  float p = expf(s - mx);
  float sm = p;
  for (int d2 = 1; d2 < 8; d2 <<= 1) sm += __shfl_xor(sm, d2, 64);
  float ai = p / (sm * 11.313708498984761f);   // softmax then /sqrt(128)
  sA[wib][q * 8 + n] = ai;
  __syncthreads();
  for (int e = lane; e < 128; e += 64){
    int q2 = e >> 4, a2 = e & 15;
    float acc = 0.f;
    #pragma unroll
    for (int n2 = 0; n2 < 8; ++n2) acc = fmaf(sA[wib][q2 * 8 + n2], sV[wib][n2 * 16 + a2], acc);
    Ui[(b * 8 + m) * 128 + e] = acc;
  }
}

// Snew = (1-lr)*Si + lr*tanh(pre + bias)
__global__ __launch_bounds__(256) void k_final_ew(const float* pre, const float* bias, const float* lr,
                                                  const float* Si, float* outSnew){
  const int t = threadIdx.x;
  for (int e = 0; e < 4; ++e){
    int idx = blockIdx.x * 1024 + e * 256 + t;
    int m = (idx >> 9) & 7, r = idx & 511;
    float v  = pre[idx] + bias[m * 512 + r];
    float tt = tanhf(v);
    float l  = lr[m];
    outSnew[idx] = (1.f - l) * Si[idx] + l * tt;
  }
}

// ---------------------------------------------------------------------------
extern "C" void kernel_launch(void* const* d_in, const int* in_sizes, int n_in,
                              void* d_out, int out_size, void* d_ws, size_t ws_size,
                              hipStream_t stream) {
  const float* Xi   = (const float*)d_in[0];
  const float* Si   = (const float*)d_in[1];
  const float* Wq   = (const float*)d_in[2];
  const float* Wk   = (const float*)d_in[3];
  const float* Wv   = (const float*)d_in[4];
  const float* Wout = (const float*)d_in[5];
  const float* W    = (const float*)d_in[6];
  const float* Win  = (const float*)d_in[7];
  const float* bias = (const float*)d_in[8];
  const float* sr   = (const float*)d_in[9];
  const float* lr   = (const float*)d_in[10];

  float* ws = (float*)d_ws;
  // chain bf16 ping-pong sets in ws[0 .. 4,194,304) floats; preb aliases
  // the same region (used only after the chain completes).
  short* Xa    = (short*)(ws + 0);         // 2M shorts (4 MB) per buffer
  short* XTa   = (short*)(ws + 1048576);
  short* Xb    = (short*)(ws + 2097152);
  short* XTb   = (short*)(ws + 3145728);
  float* preb  = ws + 0;                   // 4,194,304 floats [B,M,R]
  float* Qb    = ws + 4194304;   // 131,072
  float* Kb    = ws + 4325376;   // 1,048,576
  float* Vb    = ws + 5373952;   // 1,048,576
  float* Uib   = ws + 6422528;   // 1,048,576
  float* norm2 = ws + 7471104;   // 96
  float* sscal = ws + 7471200;   // 8

  float* outYi   = (float*)d_out;            // [1024,512]
  float* outSnew = (float*)d_out + 524288;   // [1024,8,512]

  // ---- spectral radius chain: XCD-local per-level kernels ----
  k_init<<<1, 128, 0, stream>>>(norm2);
  k_zero<<<512, 256, 0, stream>>>(outYi);    // for split-K atomic Yi epilogue
  k_prep2<<<dim3(8, 64), 256, 0, stream>>>(W, Xa, XTa, norm2);
  for (int lev = 1; lev <= NLEV; ++lev){
    const short* Xr  = (lev & 1) ? Xa  : Xb;
    const short* XTr = (lev & 1) ? XTa : XTb;
    short* Xw  = (lev & 1) ? Xb  : Xa;
    short* XTw = (lev & 1) ? XTb : XTa;
    k_sq3<<<dim3(8, 64), 256, 0, stream>>>(Xr, XTr, Xw, XTw, norm2, lev);
  }
  k_rho<<<1, 64, 0, stream>>>(norm2, sr, sscal);

  // ---- main pipeline (MFMA bf16) ----
  gemm_mfma<0><<<dim3(2, 16), 256, 0, stream>>>(AXi{Xi}, BWx{Wq}, CQ{Qb}, 512);
  gemm_mfma<0><<<dim3(2, 128), 256, 0, stream>>>(ASi{Si}, BWx{Wk}, CKV{Kb}, 512);
  gemm_mfma<0><<<dim3(2, 128), 256, 0, stream>>>(ASi{Si}, BWx{Wv}, CKV{Vb}, 512);
  k_attn<<<2048, 256, 0, stream>>>(Qb, Kb, Vb, Uib);
  gemm_mfma<0><<<dim3(8, 16, 8), 256, 0, stream>>>(APre{Uib, Si, sscal}, BPre{Win, W}, CPre{preb}, 640);
  k_final_ew<<<4096, 256, 0, stream>>>(preb, bias, lr, Si, outSnew);
  gemm_mfma<2><<<dim3(8, 16, 4), 256, 0, stream>>>(AYi{outSnew}, BYi{Wout}, CYiA{outYi}, 4096);
}

// Round 8
// 685.052 us; speedup vs baseline: 1.6536x; 1.0254x over previous
//
#include <hip/hip_runtime.h>
#include <hip/hip_bf16.h>

// Problem dims
#define B_ 1024
#define I_ 512
#define O_ 512
#define M_ 8
#define R_ 512
#define A_ 16
#define D_ 128   // M_*A_
#define NLEV 11  // squaring levels: k = 2^j, j=0..11

using bf16 = __hip_bfloat16;
typedef __attribute__((ext_vector_type(8))) short bf16x8;
typedef __attribute__((ext_vector_type(4))) float f32x4;

__device__ __forceinline__ short f2b(float x){
  __hip_bfloat16 h = __float2bfloat16(x);
  union { __hip_bfloat16 h; short s; } u; u.h = h; return u.s;
}
__device__ __forceinline__ float s2f(short s){
  union { short s[2]; float f; } u; u.s[0] = 0; u.s[1] = s; return u.f;
}

// ---------------------------------------------------------------------------
// Shared 64x64 frag-direct inner loop: A rows [m][k] bf16 (stride sa shorts),
// B rows [n][k] bf16 (stride sb). A0/B0 already include +fm*stride + fq*8.
// Depth-2 register prefetch to cover ~200-cycle L2 latency at low occupancy.
// ---------------------------------------------------------------------------
__device__ __forceinline__ void mm64_loop(const short* __restrict__ A0base,
                                          const short* __restrict__ B0base,
                                          int sa, int sb, int kiters,
                                          f32x4 (&acc)[2][2]){
  const short* A1base = A0base + 16 * (size_t)sa;
  const short* B1base = B0base + 16 * (size_t)sb;
  bf16x8 a0 = *(const bf16x8*)A0base,        a1 = *(const bf16x8*)A1base;
  bf16x8 b0 = *(const bf16x8*)B0base,        b1 = *(const bf16x8*)B1base;
  bf16x8 c0, c1, d0, d1;
  if (kiters > 1){
    c0 = *(const bf16x8*)(A0base + 32); c1 = *(const bf16x8*)(A1base + 32);
    d0 = *(const bf16x8*)(B0base + 32); d1 = *(const bf16x8*)(B1base + 32);
  }
  for (int kk = 0; kk < kiters; ++kk){
    bf16x8 na0, na1, nb0, nb1;
    if (kk + 2 < kiters){
      na0 = *(const bf16x8*)(A0base + (size_t)(kk + 2) * 32);
      na1 = *(const bf16x8*)(A1base + (size_t)(kk + 2) * 32);
      nb0 = *(const bf16x8*)(B0base + (size_t)(kk + 2) * 32);
      nb1 = *(const bf16x8*)(B1base + (size_t)(kk + 2) * 32);
    }
    acc[0][0] = __builtin_amdgcn_mfma_f32_16x16x32_bf16(a0, b0, acc[0][0], 0, 0, 0);
    acc[0][1] = __builtin_amdgcn_mfma_f32_16x16x32_bf16(a0, b1, acc[0][1], 0, 0, 0);
    acc[1][0] = __builtin_amdgcn_mfma_f32_16x16x32_bf16(a1, b0, acc[1][0], 0, 0, 0);
    acc[1][1] = __builtin_amdgcn_mfma_f32_16x16x32_bf16(a1, b1, acc[1][1], 0, 0, 0);
    a0 = c0; a1 = c1; b0 = d0; b1 = d1;
    c0 = na0; c1 = na1; d0 = nb0; d1 = nb1;
  }
}

// ---------------------------------------------------------------------------
// Prep / convert kernels
// ---------------------------------------------------------------------------
__global__ void k_init(float* norm2){
  int t = threadIdx.x;
  if (t < 8 * (NLEV + 1)) norm2[t] = 0.f;
}

__global__ __launch_bounds__(256) void k_zero(float* p){
  const int t = threadIdx.x;
  #pragma unroll
  for (int e = 0; e < 4; ++e) p[blockIdx.x * 1024 + e * 256 + t] = 0.f;
}

// SiB = bf16(Si) [8192][512]; XiB = bf16(Xi) [1024][512]
__global__ __launch_bounds__(256) void k_cvt(const float* __restrict__ Si, const float* __restrict__ Xi,
                                             short* __restrict__ SiB, short* __restrict__ XiB){
  const int t = threadIdx.x;
  #pragma unroll
  for (int e = 0; e < 8; ++e){
    int idx = blockIdx.x * 2048 + e * 256 + t;
    if (idx < 4194304) SiB[idx] = f2b(Si[idx]);
    else               XiB[idx - 4194304] = f2b(Xi[idx - 4194304]);
  }
}

// Wq/Wk/Wv [m][512][16] fp32 -> T [m][16][512] bf16. grid (3, 8)
__global__ __launch_bounds__(256) void k_tr_wqkv(const float* __restrict__ Wq, const float* __restrict__ Wk,
                                                 const float* __restrict__ Wv,
                                                 short* __restrict__ WqT, short* __restrict__ WkT,
                                                 short* __restrict__ WvT){
  __shared__ short sh[16][520];
  const int which = blockIdx.x, m = blockIdx.y, t = threadIdx.x;
  const float* src = (which == 0) ? Wq : (which == 1) ? Wk : Wv;
  short* dst = (which == 0) ? WqT : (which == 1) ? WkT : WvT;
  src += (size_t)m * 8192; dst += (size_t)m * 8192;
  #pragma unroll
  for (int l = 0; l < 32; ++l){
    int idx = l * 256 + t, i = idx >> 4, a = idx & 15;
    sh[a][i] = f2b(src[idx]);
  }
  __syncthreads();
  #pragma unroll
  for (int l = 0; l < 32; ++l){
    int idx = l * 256 + t, a = idx >> 9, i = idx & 511;
    dst[a * 512 + i] = sh[a][i];
  }
}

// Generic 64x64 transpose+convert: src fp32 [rows][SC], dst bf16 [SC][DC=rows].
// grid (SC/64, rows/64, batch)
__global__ __launch_bounds__(256) void k_trc(const float* __restrict__ src, short* __restrict__ dst,
                                             int SC, int DC, int sbatch, int dbatch){
  __shared__ short sh[64][66];
  const int t = threadIdx.x;
  const int c0 = blockIdx.x * 64, r0 = blockIdx.y * 64, z = blockIdx.z;
  src += (size_t)z * sbatch; dst += (size_t)z * dbatch;
  #pragma unroll
  for (int l = 0; l < 16; ++l){
    int idx = l * 256 + t, r = idx >> 6, c = idx & 63;
    sh[r][c] = f2b(src[(size_t)(r0 + r) * SC + c0 + c]);
  }
  __syncthreads();
  #pragma unroll
  for (int l = 0; l < 16; ++l){
    int idx = l * 256 + t, r = idx >> 6, c = idx & 63;
    dst[(size_t)(c0 + r) * DC + r0 + c] = sh[c][r];
  }
}

// W fp32 -> X0 bf16 + X0^T bf16 (+ persistent W^T bf16 copy) + norm2[0]
__global__ __launch_bounds__(256) void k_prep2(const float* __restrict__ W, short* __restrict__ X,
                                               short* __restrict__ XT, short* __restrict__ WTp,
                                               float* __restrict__ norm2){
  __shared__ short Tr[64][66];
  const int u = blockIdx.x, tile = blockIdx.y;
  const int row0 = (tile >> 3) * 64, col0 = (tile & 7) * 64;
  const size_t off = (size_t)u * (R_ * R_);
  const int t = threadIdx.x, lane = t & 63;
  float ss = 0.f;
  #pragma unroll
  for (int l = 0; l < 16; ++l){
    int idx = l * 256 + t, r = idx >> 6, c = idx & 63;
    short b = f2b(W[off + (size_t)(row0 + r) * R_ + col0 + c]);
    float vb = s2f(b);
    ss = fmaf(vb, vb, ss);
    X[off + (size_t)(row0 + r) * R_ + col0 + c] = b;
    Tr[r][c] = b;
  }
  __syncthreads();
  #pragma unroll
  for (int l = 0; l < 16; ++l){
    int idx = l * 256 + t, r = idx >> 6, c = idx & 63;
    short v = Tr[c][r];
    XT [off + (size_t)(col0 + r) * R_ + row0 + c] = v;
    WTp[off + (size_t)(col0 + r) * R_ + row0 + c] = v;
  }
  #pragma unroll
  for (int o = 32; o > 0; o >>= 1) ss += __shfl_xor(ss, o, 64);
  if (lane == 0) atomicAdd(&norm2[u], ss);
}

// ---------------------------------------------------------------------------
// Eigen chain squaring level (XCD-local, frag-direct, depth-2 prefetch)
// ---------------------------------------------------------------------------
__global__ __launch_bounds__(256) void k_sq3(const short* __restrict__ Xr, const short* __restrict__ XTr,
                                             short* __restrict__ Xw, short* __restrict__ XTw,
                                             float* __restrict__ norm2, int lev){
  __shared__ short Tr[64][66];
  const int u = blockIdx.x, tile = blockIdx.y;     // blockIdx.x = unit -> XCD-local
  const int row0 = (tile >> 3) * 64, col0 = (tile & 7) * 64;
  const size_t off = (size_t)u * (R_ * R_);
  const int t = threadIdx.x, wv = t >> 6, lane = t & 63;
  const int wr = (wv >> 1) * 32, wc = (wv & 1) * 32;
  const int fm = lane & 15, fq = lane >> 4, ko = fq * 8;
  const float s2 = 1.f / norm2[(lev - 1) * 8 + u];
  const short* A0 = Xr  + off + (size_t)(row0 + wr + fm) * R_ + ko;
  const short* B0 = XTr + off + (size_t)(col0 + wc + fm) * R_ + ko;
  f32x4 zz = {0.f, 0.f, 0.f, 0.f};
  f32x4 acc[2][2] = {{zz, zz}, {zz, zz}};
  mm64_loop(A0, B0, R_, R_, 16, acc);
  float ss = 0.f;
  #pragma unroll
  for (int i = 0; i < 2; ++i)
    #pragma unroll
    for (int j = 0; j < 2; ++j)
      #pragma unroll
      for (int r = 0; r < 4; ++r){
        int lr = wr + i * 16 + fq * 4 + r, lc = wc + j * 16 + fm;
        short b = f2b(acc[i][j][r] * s2);
        float vb = s2f(b);
        ss = fmaf(vb, vb, ss);
        Xw[off + (size_t)(row0 + lr) * R_ + col0 + lc] = b;
        Tr[lr][lc] = b;
      }
  __syncthreads();
  #pragma unroll
  for (int l = 0; l < 16; ++l){
    int idx = l * 256 + t, r = idx >> 6, c = idx & 63;
    XTw[off + (size_t)(col0 + r) * R_ + row0 + c] = Tr[c][r];
  }
  #pragma unroll
  for (int o = 32; o > 0; o >>= 1) ss += __shfl_xor(ss, o, 64);
  if (lane == 0) atomicAdd(&norm2[lev * 8 + u], ss);
}

// L_j = 2 L_{j-1} + 0.5 ln n2_j ; lnrho = (L11 - 2 L10 + L9)/512
__global__ void k_rho(const float* norm2, const float* sr, float* sscale){
  int t = threadIdx.x;
  if (t < 8){
    float L = 0.5f * logf(norm2[t]);
    float L9 = 0.f, L10 = 0.f, L11 = 0.f;
    for (int j = 1; j <= NLEV; ++j){
      L = 2.f * L + 0.5f * logf(norm2[j * 8 + t]);
      if (j == 9)  L9  = L;
      if (j == 10) L10 = L;
      if (j == 11) L11 = L;
    }
    float lnr = (L11 - 2.f * L10 + L9) * (1.f / 512.f);
    sscale[t] = sr[t] / expf(lnr);
  }
}

// ---------------------------------------------------------------------------
// Fused QKV GEMM: z=0 K, z=1 V, z=2 Q (y<16). A rows contiguous bf16.
// ---------------------------------------------------------------------------
__global__ __launch_bounds__(256) void k_qkv(const short* __restrict__ SiB, const short* __restrict__ XiB,
                                             const short* __restrict__ WqT, const short* __restrict__ WkT,
                                             const short* __restrict__ WvT,
                                             float* __restrict__ Kb, float* __restrict__ Vb,
                                             float* __restrict__ Qb){
  const int z = blockIdx.z;
  if (z == 2 && blockIdx.y >= 16) return;
  const int t = threadIdx.x, wv = t >> 6, lane = t & 63;
  const int wr = (wv >> 1) * 32, wc = (wv & 1) * 32;
  const int fm = lane & 15, fq = lane >> 4, ko = fq * 8;
  const int row0 = blockIdx.y * 64, col0 = blockIdx.x * 64;
  const short* Abase = (z == 2) ? XiB : SiB;
  const short* Bbase = (z == 0) ? WkT : (z == 1) ? WvT : WqT;
  const short* A0 = Abase + (size_t)(row0 + wr + fm) * 512 + ko;
  const short* B0 = Bbase + (size_t)(col0 + wc + fm) * 512 + ko;
  f32x4 zz = {0.f, 0.f, 0.f, 0.f};
  f32x4 acc[2][2] = {{zz, zz}, {zz, zz}};
  mm64_loop(A0, B0, 512, 512, 16, acc);
  float* dst = (z == 0) ? Kb : (z == 1) ? Vb : Qb;
  #pragma unroll
  for (int i = 0; i < 2; ++i)
    #pragma unroll
    for (int j = 0; j < 2; ++j)
      #pragma unroll
      for (int r = 0; r < 4; ++r){
        int row = row0 + wr + i * 16 + fq * 4 + r;
        int col = col0 + wc + j * 16 + fm;
        float v = acc[i][j][r];
        if (z == 2) dst[row * 128 + col];
        if (z == 2) dst[row * 128 + col] = v;
        else {
          int b = row >> 3, n = row & 7, mc = col >> 4, a = col & 15;
          dst[b * 1024 + mc * 128 + n * 16 + a] = v;
        }
      }
}

// ---------------------------------------------------------------------------
// Attention: one wave per (b,m); writes Ui as bf16 [bm][128].
// ---------------------------------------------------------------------------
__global__ __launch_bounds__(256) void k_attn(const float* Q, const float* K, const float* V, short* UiB){
  __shared__ float sQ[4][128], sK[4][128], sV[4][128], sA[4][64];
  const int wib = threadIdx.x >> 6, lane = threadIdx.x & 63;
  const int w = blockIdx.x * 4 + wib;
  const int b = w >> 3, m = w & 7;
  for (int e = lane; e < 128; e += 64){
    sQ[wib][e] = Q[b * 128 + e];
    sK[wib][e] = K[b * 1024 + m * 128 + e];
    sV[wib][e] = V[b * 1024 + m * 128 + e];
  }
  __syncthreads();
  const int q = lane >> 3, n = lane & 7;
  float s = 0.f;
  #pragma unroll
  for (int a = 0; a < 16; ++a) s = fmaf(sQ[wib][q * 16 + a], sK[wib][n * 16 + a], s);
  float mx = s;
  for (int d2 = 1; d2 < 8; d2 <<= 1) mx = fmaxf(mx, __shfl_xor(mx, d2, 64));
  float p = expf(s - mx);
  float sm = p;
  for (int d2 = 1; d2 < 8; d2 <<= 1) sm += __shfl_xor(sm, d2, 64);
  float ai = p / (sm * 11.313708498984761f);   // softmax then /sqrt(128)
  sA[wib][q * 8 + n] = ai;
  __syncthreads();
  for (int e = lane; e < 128; e += 64){
    int q2 = e >> 4, a2 = e & 15;
    float acc = 0.f;
    #pragma unroll
    for (int n2 = 0; n2 < 8; ++n2) acc = fmaf(sA[wib][q2 * 8 + n2], sV[wib][n2 * 16 + a2], acc);
    UiB[(b * 8 + m) * 128 + e] = f2b(acc);
  }
}

// ---------------------------------------------------------------------------
// Pre-GEMM (fused final elementwise): per unit m = blockIdx.z.
// accA = Ui@WinT (K=128), accB = Si@W^T (K=512); out = accA + sc[m]*accB,
// then Snew = (1-lr)*Si + lr*tanh(out + bias) -> outSnew fp32 + SnewB bf16.
// ---------------------------------------------------------------------------
__global__ __launch_bounds__(256) void k_pre(const short* __restrict__ UiB, const short* __restrict__ SiB,
                                             const short* __restrict__ WinT, const short* __restrict__ WTp,
                                             const float* __restrict__ sscal, const float* __restrict__ bias,
                                             const float* __restrict__ lr, const float* __restrict__ Si,
                                             float* __restrict__ outSnew, short* __restrict__ SnewB){
  const int m = blockIdx.z;
  const int t = threadIdx.x, wv = t >> 6, lane = t & 63;
  const int wr = (wv >> 1) * 32, wc = (wv & 1) * 32;
  const int fm = lane & 15, fq = lane >> 4, ko = fq * 8;
  const int row0 = blockIdx.y * 64, col0 = blockIdx.x * 64;   // rows = b, cols = r
  f32x4 zz = {0.f, 0.f, 0.f, 0.f};
  f32x4 accA[2][2] = {{zz, zz}, {zz, zz}};
  f32x4 accB[2][2] = {{zz, zz}, {zz, zz}};
  {
    const short* A0 = UiB + ((size_t)(row0 + wr + fm) * 8 + m) * 128 + ko;
    const short* B0 = WinT + (size_t)m * (512 * 128) + (size_t)(col0 + wc + fm) * 128 + ko;
    mm64_loop(A0, B0, 8 * 128, 128, 4, accA);
  }
  {
    const short* A0 = SiB + ((size_t)(row0 + wr + fm) * 8 + m) * 512 + ko;
    const short* B0 = WTp + (size_t)m * (R_ * R_) + (size_t)(col0 + wc + fm) * 512 + ko;
    mm64_loop(A0, B0, 8 * 512, 512, 16, accB);
  }
  const float sc = sscal[m], lm = lr[m];
  #pragma unroll
  for (int i = 0; i < 2; ++i)
    #pragma unroll
    for (int j = 0; j < 2; ++j)
      #pragma unroll
      for (int r = 0; r < 4; ++r){
        int b = row0 + wr + i * 16 + fq * 4 + r;
        int c = col0 + wc + j * 16 + fm;
        size_t g = ((size_t)b * 8 + m) * 512 + c;
        float pre = accA[i][j][r] + sc * accB[i][j][r];
        float v = pre + bias[m * 512 + c];
        float sn = (1.f - lm) * Si[g] + lm * tanhf(v);
        outSnew[g] = sn;
        SnewB[g] = f2b(sn);
      }
}

// ---------------------------------------------------------------------------
// Yi GEMM: A = SnewB [1024][4096], B = WoutT [512][4096]; split-K=4 atomics.
// ---------------------------------------------------------------------------
__global__ __launch_bounds__(256) void k_yi(const short* __restrict__ SnewB, const short* __restrict__ WoutT,
                                            float* __restrict__ outYi){
  const int t = threadIdx.x, wv = t >> 6, lane = t & 63;
  const int wr = (wv >> 1) * 32, wc = (wv & 1) * 32;
  const int fm = lane & 15, fq = lane >> 4, ko = fq * 8;
  const int row0 = blockIdx.y * 64, col0 = blockIdx.x * 64;
  const int kbeg = blockIdx.z * 1024;
  const short* A0 = SnewB + (size_t)(row0 + wr + fm) * 4096 + kbeg + ko;
  const short* B0 = WoutT + (size_t)(col0 + wc + fm) * 4096 + kbeg + ko;
  f32x4 zz = {0.f, 0.f, 0.f, 0.f};
  f32x4 acc[2][2] = {{zz, zz}, {zz, zz}};
  mm64_loop(A0, B0, 4096, 4096, 32, acc);
  #pragma unroll
  for (int i = 0; i < 2; ++i)
    #pragma unroll
    for (int j = 0; j < 2; ++j)
      #pragma unroll
      for (int r = 0; r < 4; ++r){
        int row = row0 + wr + i * 16 + fq * 4 + r;
        int col = col0 + wc + j * 16 + fm;
        atomicAdd(&outYi[row * 512 + col], acc[i][j][r]);
      }
}

// ---------------------------------------------------------------------------
extern "C" void kernel_launch(void* const* d_in, const int* in_sizes, int n_in,
                              void* d_out, int out_size, void* d_ws, size_t ws_size,
                              hipStream_t stream) {
  const float* Xi   = (const float*)d_in[0];
  const float* Si   = (const float*)d_in[1];
  const float* Wq   = (const float*)d_in[2];
  const float* Wk   = (const float*)d_in[3];
  const float* Wv   = (const float*)d_in[4];
  const float* Wout = (const float*)d_in[5];
  const float* W    = (const float*)d_in[6];
  const float* Win  = (const float*)d_in[7];
  const float* bias = (const float*)d_in[8];
  const float* sr   = (const float*)d_in[9];
  const float* lr   = (const float*)d_in[10];

  float* ws = (float*)d_ws;
  short* Xa    = (short*)(ws + 0);         // chain ping-pong, 1,048,576 floats each
  short* XTa   = (short*)(ws + 1048576);
  short* Xb    = (short*)(ws + 2097152);
  short* XTb   = (short*)(ws + 3145728);
  short* WTp   = (short*)(ws + 4194304);   // persistent bf16 W^T
  short* SiB   = (short*)(ws + 5242880);   // [8192][512] bf16
  short* XiB   = (short*)(ws + 7340032);   // [1024][512] bf16
  short* WqT   = (short*)(ws + 7602176);   // [m][16][512] bf16
  short* WkT   = (short*)(ws + 7634944);
  short* WvT   = (short*)(ws + 7667712);
  short* WinT  = (short*)(ws + 7700480);   // [m][512][128] bf16
  short* WoutT = (short*)(ws + 7962624);   // [512][4096] bf16
  float* Qb    = ws + 9011200;             // [1024][128] fp32
  float* Kb    = ws + 9142272;             // [B,M,N,A] fp32
  float* Vb    = ws + 10190848;
  short* UiB   = (short*)(ws + 11239424);  // [8192][128] bf16
  short* SnewB = (short*)(ws + 11763712);  // [1024][4096] bf16
  float* norm2 = ws + 13860864;            // 96
  float* sscal = ws + 13860960;            // 8
  // total ~55.4 MB; harness poison shows ws >= 256 MB

  float* outYi   = (float*)d_out;            // [1024,512]
  float* outSnew = (float*)d_out + 524288;   // [1024,8,512]

  // ---- prep / converts (independent of chain) ----
  k_init<<<1, 128, 0, stream>>>(norm2);
  k_zero<<<512, 256, 0, stream>>>(outYi);
  k_cvt<<<2304, 256, 0, stream>>>(Si, Xi, SiB, XiB);
  k_tr_wqkv<<<dim3(3, 8), 256, 0, stream>>>(Wq, Wk, Wv, WqT, WkT, WvT);
  k_trc<<<dim3(8, 2, 8), 256, 0, stream>>>(Win, WinT, 512, 128, 65536, 65536);
  k_trc<<<dim3(8, 64, 1), 256, 0, stream>>>(Wout, WoutT, 512, 4096, 0, 0);

  // ---- spectral radius chain ----
  k_prep2<<<dim3(8, 64), 256, 0, stream>>>(W, Xa, XTa, WTp, norm2);
  for (int lev = 1; lev <= NLEV; ++lev){
    const short* Xr  = (lev & 1) ? Xa  : Xb;
    const short* XTr = (lev & 1) ? XTa : XTb;
    short* Xw  = (lev & 1) ? Xb  : Xa;
    short* XTw = (lev & 1) ? XTb : XTa;
    k_sq3<<<dim3(8, 64), 256, 0, stream>>>(Xr, XTr, Xw, XTw, norm2, lev);
  }
  k_rho<<<1, 64, 0, stream>>>(norm2, sr, sscal);

  // ---- main pipeline (frag-direct bf16) ----
  k_qkv<<<dim3(2, 128, 3), 256, 0, stream>>>(SiB, XiB, WqT, WkT, WvT, Kb, Vb, Qb);
  k_attn<<<2048, 256, 0, stream>>>(Qb, Kb, Vb, UiB);
  k_pre<<<dim3(8, 16, 8), 256, 0, stream>>>(UiB, SiB, WinT, WTp, sscal, bias, lr, Si, outSnew, SnewB);
  k_yi<<<dim3(8, 16, 4), 256, 0, stream>>>(SnewB, WoutT, outYi);
}